// Round 1
// baseline (8695.071 us; speedup 1.0000x reference)
//
#include <hip/hip_runtime.h>
#include <hip/hip_bf16.h>

#define L_ 4
#define B_ 256
#define C_ 512
#define S_ 64
#define N_ 50000
#define K_ 20
#define NLIST 21      // K+1 smallest kept
#define NC_ 32        // n-chunks per l
#define CHUNK_ 1563   // ceil(N/NC)
#define LPAD 24       // padded list stride in workspace
#define BIGF 3.0e38f

// ---------------- Phase 1: q[l][b][c] = mean_s feats[l][b][c][s] ----------------
// One wave handles 4 rows of 64 floats via float4 (16B/lane, fully coalesced).
__global__ void qmean_kernel(const float* __restrict__ feats, float* __restrict__ q)
{
    int gtid = blockIdx.x * 256 + threadIdx.x;
    int wid  = gtid >> 6;
    int lane = threadIdx.x & 63;
    const float4* src = reinterpret_cast<const float4*>(feats) + (size_t)wid * 64 + lane;
    float4 v = *src;
    float s = v.x + v.y + v.z + v.w;
    s += __shfl_xor(s, 1);
    s += __shfl_xor(s, 2);
    s += __shfl_xor(s, 4);
    s += __shfl_xor(s, 8);
    if ((lane & 15) == 0) q[wid * 4 + (lane >> 4)] = s * (1.0f / 64.0f);
}

// ---------------- Phase 2: tiled cross-GEMM + streaming top-21 per query --------
// Block = (l, n-chunk, q-tile of 64 rows). 256 threads, 64x64 tile, KC=32.
// Maintains s = b2 - 2*cross (q2 added later; monotone per row -> same top-k).
__global__ void dist_topk_kernel(const float* __restrict__ bank,
                                 const float* __restrict__ q,
                                 float* __restrict__ lists)
{
    // smem regions (floats):
    //   qs     [64][36]  @ 0      (row stride 36 -> 144B, 16B aligned)
    //   bs     [64][36]  @ 2304
    //   sd     [64][65]  @ 4608   (odd stride -> conflict-free row scan)
    //   b2s    [64]      @ 8768
    //   b2part [64][8]   @ 8832
    //   mg     [256][22] @ 0      (aliases qs/bs/sd, used only after final barrier)
    __shared__ __align__(16) float smem[9344];

    const int tid = threadIdx.x;
    const int qt  = blockIdx.x & 3;
    const int nc  = (blockIdx.x >> 2) & 31;
    const int l   = blockIdx.x >> 7;

    const float* qb = q    + ((size_t)l * B_ + qt * 64) * C_;
    const float* bb = bank + (size_t)l * N_ * C_;

    const int n0 = nc * CHUNK_;
    const int n1 = (n0 + CHUNK_ < N_) ? (n0 + CHUNK_) : N_;

    const int tx = tid & 15;   // bank-col group
    const int ty = tid >> 4;   // q-row group
    const int sr = tid >> 3;   // staging row 0..31 (and +32)
    const int sp = (tid & 7) << 2;  // staging float offset 0..28

    float list[NLIST];
#pragma unroll
    for (int i = 0; i < NLIST; ++i) list[i] = BIGF;

    for (int nt = n0; nt < n1; nt += 64) {
        const int ncols = (n1 - nt < 64) ? (n1 - nt) : 64;

        float acc[4][4];
#pragma unroll
        for (int m = 0; m < 4; ++m)
#pragma unroll
            for (int n = 0; n < 4; ++n) acc[m][n] = 0.0f;

        float b2p0 = 0.0f, b2p1 = 0.0f;

        for (int kc = 0; kc < C_; kc += 32) {
            float4 qv0 = *reinterpret_cast<const float4*>(qb + (size_t)sr * C_ + kc + sp);
            float4 qv1 = *reinterpret_cast<const float4*>(qb + (size_t)(sr + 32) * C_ + kc + sp);
            const int gr0 = nt + sr, gr1 = nt + sr + 32;
            float4 bv0 = make_float4(0.f, 0.f, 0.f, 0.f);
            float4 bv1 = make_float4(0.f, 0.f, 0.f, 0.f);
            if (gr0 < n1) bv0 = *reinterpret_cast<const float4*>(bb + (size_t)gr0 * C_ + kc + sp);
            if (gr1 < n1) bv1 = *reinterpret_cast<const float4*>(bb + (size_t)gr1 * C_ + kc + sp);
            b2p0 += bv0.x * bv0.x + bv0.y * bv0.y + bv0.z * bv0.z + bv0.w * bv0.w;
            b2p1 += bv1.x * bv1.x + bv1.y * bv1.y + bv1.z * bv1.z + bv1.w * bv1.w;

            __syncthreads();  // previous compute's LDS reads done
            *reinterpret_cast<float4*>(&smem[sr * 36 + sp])               = qv0;
            *reinterpret_cast<float4*>(&smem[(sr + 32) * 36 + sp])        = qv1;
            *reinterpret_cast<float4*>(&smem[2304 + sr * 36 + sp])        = bv0;
            *reinterpret_cast<float4*>(&smem[2304 + (sr + 32) * 36 + sp]) = bv1;
            __syncthreads();

#pragma unroll
            for (int k4 = 0; k4 < 32; k4 += 4) {
                float4 qf[4], bf[4];
#pragma unroll
                for (int m = 0; m < 4; ++m)
                    qf[m] = *reinterpret_cast<const float4*>(&smem[(ty + 16 * m) * 36 + k4]);
#pragma unroll
                for (int n = 0; n < 4; ++n)
                    bf[n] = *reinterpret_cast<const float4*>(&smem[2304 + (tx + 16 * n) * 36 + k4]);
#pragma unroll
                for (int m = 0; m < 4; ++m)
#pragma unroll
                    for (int n = 0; n < 4; ++n)
                        acc[m][n] += qf[m].x * bf[n].x + qf[m].y * bf[n].y
                                   + qf[m].z * bf[n].z + qf[m].w * bf[n].w;
            }
        }

        // deterministic b2 reduction (no atomics -> replay-deterministic)
        smem[8832 + sr * 8 + (tid & 7)]        = b2p0;
        smem[8832 + (sr + 32) * 8 + (tid & 7)] = b2p1;
        __syncthreads();
        if (tid < 64) {
            float s = 0.0f;
#pragma unroll
            for (int j = 0; j < 8; ++j) s += smem[8832 + tid * 8 + j];
            smem[8768 + tid] = s;
        }
        __syncthreads();

        // dump s = b2 - 2*cross into sd
#pragma unroll
        for (int m = 0; m < 4; ++m)
#pragma unroll
            for (int n = 0; n < 4; ++n)
                smem[4608 + (ty + 16 * m) * 65 + (tx + 16 * n)] =
                    smem[8768 + tx + 16 * n] - 2.0f * acc[m][n];
        __syncthreads();

        // scan: 4 lanes per row, each scans 16 cols into its private sorted-21 list
        {
            const int srow  = tid >> 2;
            const int sbase = (tid & 3) * 16;
#pragma unroll 1
            for (int j = 0; j < 16; ++j) {
                const int c = sbase + j;
                if (c < ncols) {
                    float v = smem[4608 + srow * 65 + c];
                    if (v < list[NLIST - 1]) {
#pragma unroll
                        for (int i = 0; i < NLIST; ++i) {
                            const float lo = fminf(list[i], v);
                            const float hi = fmaxf(list[i], v);
                            list[i] = lo;
                            v = hi;
                        }
                    }
                }
            }
        }
        __syncthreads();  // scan done before next tile overwrites LDS
    }

    // merge the 4 per-lane sub-lists of each row -> sorted 21, write to workspace
#pragma unroll
    for (int i = 0; i < NLIST; ++i) smem[tid * 22 + i] = list[i];
    __syncthreads();

    if ((tid & 3) == 0) {
        const int row = tid >> 2;
        float* outp = lists + ((size_t)((l * B_) + qt * 64 + row) * NC_ + nc) * LPAD;
        int p0 = 0, p1 = 0, p2 = 0, p3 = 0;
#pragma unroll 1
        for (int i = 0; i < NLIST; ++i) {
            const float h0 = (p0 < NLIST) ? smem[(tid + 0) * 22 + p0] : BIGF;
            const float h1 = (p1 < NLIST) ? smem[(tid + 1) * 22 + p1] : BIGF;
            const float h2 = (p2 < NLIST) ? smem[(tid + 2) * 22 + p2] : BIGF;
            const float h3 = (p3 < NLIST) ? smem[(tid + 3) * 22 + p3] : BIGF;
            const float mv = fminf(fminf(h0, h1), fminf(h2, h3));
            if (h0 == mv)      ++p0;
            else if (h1 == mv) ++p1;
            else if (h2 == mv) ++p2;
            else               ++p3;
            outp[i] = mv;
        }
    }
}

// ---------------- Phase 3: merge 32 sorted chunk-lists per (l,b), compute LID ----
__global__ void lid_kernel(const float* __restrict__ lists,
                           const float* __restrict__ q,
                           float* __restrict__ out)
{
    __shared__ float pops[4][NLIST];
    const int lane = threadIdx.x & 63;
    const int w    = threadIdx.x >> 6;
    const int gw   = blockIdx.x * 4 + w;   // 0..1023 = (l,b)
    const int l    = gw & 3;
    const int b    = gw >> 2;

    // q2 for this query
    const float* qr = q + ((size_t)l * B_ + b) * C_;
    float q2 = 0.0f;
#pragma unroll
    for (int i = 0; i < 8; ++i) {
        const float v = qr[lane + (i << 6)];
        q2 += v * v;
    }
    q2 += __shfl_xor(q2, 1);
    q2 += __shfl_xor(q2, 2);
    q2 += __shfl_xor(q2, 4);
    q2 += __shfl_xor(q2, 8);
    q2 += __shfl_xor(q2, 16);
    q2 += __shfl_xor(q2, 32);

    // 32-way merge of sorted lists via pop-min; lane nc owns chunk nc's list
    const float* lb = lists + (size_t)((l * B_ + b) * NC_) * LPAD;
    int ptr = 0;
#pragma unroll 1
    for (int i = 0; i < NLIST; ++i) {
        float h = (lane < NC_ && ptr < NLIST) ? lb[lane * LPAD + ptr] : BIGF;
        float m = h;
        m = fminf(m, __shfl_xor(m, 1));
        m = fminf(m, __shfl_xor(m, 2));
        m = fminf(m, __shfl_xor(m, 4));
        m = fminf(m, __shfl_xor(m, 8));
        m = fminf(m, __shfl_xor(m, 16));
        m = fminf(m, __shfl_xor(m, 32));
        const unsigned long long ball = __ballot(h == m);
        if (lane == __ffsll(ball) - 1) ++ptr;       // only lowest tying lane advances
        if (lane == 0) pops[w][i] = fmaxf(q2 + m, 0.0f);  // d2, clamped like reference
    }
    __syncthreads();

    const float r2 = pops[w][NLIST - 1];
    float t = 0.0f;
    if (lane >= 1 && lane < NLIST) t = 0.5f * logf(pops[w][lane] / r2);
    t += __shfl_xor(t, 1);
    t += __shfl_xor(t, 2);
    t += __shfl_xor(t, 4);
    t += __shfl_xor(t, 8);
    t += __shfl_xor(t, 16);
    t += __shfl_xor(t, 32);

    if (lane == 0) out[(size_t)b * L_ + l] = -(float)K_ / t;  // output is (B, L)
}

extern "C" void kernel_launch(void* const* d_in, const int* in_sizes, int n_in,
                              void* d_out, int out_size, void* d_ws, size_t ws_size,
                              hipStream_t stream)
{
    (void)in_sizes; (void)n_in; (void)out_size; (void)ws_size;
    const float* feats = (const float*)d_in[0];
    const float* bank  = (const float*)d_in[1];
    // workspace layout: q (L*B*C floats = 2 MiB), then chunk lists (L*B*NC*LPAD = 3 MiB)
    float* q     = (float*)d_ws;
    float* lists = q + (size_t)L_ * B_ * C_;

    // L*B*C rows / 4 rows-per-wave / 4 waves-per-block = 32768 blocks
    qmean_kernel<<<32768, 256, 0, stream>>>(feats, q);
    // 4 q-tiles (fastest, share bank stream) x 32 n-chunks x 4 l
    dist_topk_kernel<<<512, 256, 0, stream>>>(bank, q, lists);
    // one wave per (l,b)
    lid_kernel<<<256, 256, 0, stream>>>(lists, q, (float*)d_out);
}

// Round 2
// 391.367 us; speedup vs baseline: 22.2172x; 22.2172x over previous
//
#include <hip/hip_runtime.h>
#include <hip/hip_bf16.h>

#define L_ 4
#define B_ 256
#define C_ 512
#define N_ 50000
#define K_ 20
#define NLIST 21      // K+1 smallest kept
#define NC_ 32        // n-chunks per l
#define CHUNK_ 1563   // ceil(N/NC)
#define LPAD 24       // padded list stride in workspace
#define BIGF 3.0e38f

#define BM 64         // q-rows per block
#define BN 128        // bank-cols per block
#define KSTEP 64
#define QS_STR 72     // bf16 units (pad: 144B rows -> 2-way max on b128 frag reads)
#define BS_STR 72
#define SD_STR 129    // f32 units

// LDS byte offsets
#define QS_OFF   0        // 64*72*2   = 9216
#define BS_OFF   9216     // 128*72*2  = 18432 -> ends 27648
#define SD_OFF   27648    // 64*129*4  = 33024 -> ends 60672
#define B2P_OFF  60672    // 128*4*4   = 2048  -> 62720
#define B2S_OFF  62720    // 128*4     = 512   -> 63232
#define MG_OFF   0        // 256*22*4  = 22528 (aliases qs/bs, used after final barrier)
#define SMEM_BYTES 63232

typedef __attribute__((ext_vector_type(8))) short short8;
typedef __attribute__((ext_vector_type(4))) float f32x4;

// ---------------- Phase 1: q[l][b][c] = mean_s feats[l][b][c][s] ----------------
__global__ void qmean_kernel(const float* __restrict__ feats, float* __restrict__ q)
{
    int gtid = blockIdx.x * 256 + threadIdx.x;
    int wid  = gtid >> 6;
    int lane = threadIdx.x & 63;
    const float4* src = reinterpret_cast<const float4*>(feats) + (size_t)wid * 64 + lane;
    float4 v = *src;
    float s = v.x + v.y + v.z + v.w;
    s += __shfl_xor(s, 1);
    s += __shfl_xor(s, 2);
    s += __shfl_xor(s, 4);
    s += __shfl_xor(s, 8);
    if ((lane & 15) == 0) q[wid * 4 + (lane >> 4)] = s * (1.0f / 64.0f);
}

// ---------------- Phase 2: MFMA bf16 cross-GEMM + streaming top-21 --------------
__device__ inline unsigned pk2(float lo, float hi) {
    __hip_bfloat162 h = __float22bfloat162_rn(make_float2(lo, hi));
    return *reinterpret_cast<unsigned*>(&h);
}

__device__ inline void cvt_store16(unsigned short* dst, float4 f0, float4 f1,
                                   float4 f2, float4 f3) {
    union { short8 s; unsigned u[4]; } p0, p1;
    p0.u[0] = pk2(f0.x, f0.y); p0.u[1] = pk2(f0.z, f0.w);
    p0.u[2] = pk2(f1.x, f1.y); p0.u[3] = pk2(f1.z, f1.w);
    p1.u[0] = pk2(f2.x, f2.y); p1.u[1] = pk2(f2.z, f2.w);
    p1.u[2] = pk2(f3.x, f3.y); p1.u[3] = pk2(f3.z, f3.w);
    *reinterpret_cast<short8*>(dst)     = p0.s;
    *reinterpret_cast<short8*>(dst + 8) = p1.s;
}

__global__ __launch_bounds__(256, 2)
void dist_topk_kernel(const float* __restrict__ bank,
                      const float* __restrict__ q,
                      float* __restrict__ lists)
{
    __shared__ __align__(16) unsigned char smem[SMEM_BYTES];
    unsigned short* qs = (unsigned short*)(smem + QS_OFF);
    unsigned short* bs = (unsigned short*)(smem + BS_OFF);
    float* sd  = (float*)(smem + SD_OFF);
    float* b2p = (float*)(smem + B2P_OFF);
    float* b2s = (float*)(smem + B2S_OFF);
    float* mg  = (float*)(smem + MG_OFF);

    const int tid = threadIdx.x;
    const int qt  = blockIdx.x & 3;
    const int nc  = (blockIdx.x >> 2) & 31;
    const int l   = blockIdx.x >> 7;

    const float* qb = q    + ((size_t)l * B_ + qt * 64) * C_;
    const float* bb = bank + (size_t)l * N_ * C_;

    const int n0 = nc * CHUNK_;
    const int n1 = (n0 + CHUNK_ < N_) ? (n0 + CHUNK_) : N_;

    const int lane = tid & 63;
    const int wid  = tid >> 6;
    const int wy   = wid >> 1;          // 0..1: q-row half (32 rows)
    const int wx   = wid & 1;           // 0..1: bank-col half (64 cols)

    const int srow = tid >> 2;          // staging row 0..63
    const int sks  = (tid & 3) << 4;    // staging k offset (floats): 0,16,32,48

    const int c_lo = lane & 15;
    const int r_hi = lane >> 4;

    float list[NLIST];
#pragma unroll
    for (int i = 0; i < NLIST; ++i) list[i] = BIGF;

    for (int nt = n0; nt < n1; nt += BN) {
        const int ncols = (n1 - nt < BN) ? (n1 - nt) : BN;

        f32x4 acc[2][4];
#pragma unroll
        for (int m = 0; m < 2; ++m)
#pragma unroll
            for (int n = 0; n < 4; ++n) acc[m][n] = (f32x4){0.f, 0.f, 0.f, 0.f};

        float b2acc0 = 0.f, b2acc1 = 0.f;

        for (int kb = 0; kb < C_; kb += KSTEP) {
            __syncthreads();   // previous sub-step's LDS reads complete
            // --- stage q tile (64 x 64 fp32 -> bf16) ---
            {
                const float* src = qb + (size_t)srow * C_ + kb + sks;
                float4 f0 = *reinterpret_cast<const float4*>(src);
                float4 f1 = *reinterpret_cast<const float4*>(src + 4);
                float4 f2 = *reinterpret_cast<const float4*>(src + 8);
                float4 f3 = *reinterpret_cast<const float4*>(src + 12);
                cvt_store16(qs + srow * QS_STR + sks, f0, f1, f2, f3);
            }
            // --- stage bank tile (128 x 64 fp32 -> bf16), 2 passes, fold b2 ---
#pragma unroll
            for (int p = 0; p < 2; ++p) {
                const int r  = srow + (p << 6);
                const int gr = nt + r;
                float4 f0 = make_float4(0.f,0.f,0.f,0.f), f1 = f0, f2 = f0, f3 = f0;
                if (gr < n1) {
                    const float* src = bb + (size_t)gr * C_ + kb + sks;
                    f0 = *reinterpret_cast<const float4*>(src);
                    f1 = *reinterpret_cast<const float4*>(src + 4);
                    f2 = *reinterpret_cast<const float4*>(src + 8);
                    f3 = *reinterpret_cast<const float4*>(src + 12);
                }
                const float s2 = f0.x*f0.x + f0.y*f0.y + f0.z*f0.z + f0.w*f0.w
                               + f1.x*f1.x + f1.y*f1.y + f1.z*f1.z + f1.w*f1.w
                               + f2.x*f2.x + f2.y*f2.y + f2.z*f2.z + f2.w*f2.w
                               + f3.x*f3.x + f3.y*f3.y + f3.z*f3.z + f3.w*f3.w;
                if (p == 0) b2acc0 += s2; else b2acc1 += s2;
                cvt_store16(bs + r * BS_STR + sks, f0, f1, f2, f3);
            }
            __syncthreads();
            // --- MFMA: wave tile 32(m) x 64(n), K=64 in two k32 halves ---
            const unsigned short* qrow = qs + (32*wy + c_lo) * QS_STR + (r_hi << 3);
            const unsigned short* brow = bs + (64*wx + c_lo) * BS_STR + (r_hi << 3);
#pragma unroll
            for (int kh = 0; kh < 2; ++kh) {
                short8 a0 = *reinterpret_cast<const short8*>(qrow + kh*32);
                short8 a1 = *reinterpret_cast<const short8*>(qrow + 16*QS_STR + kh*32);
                short8 b0 = *reinterpret_cast<const short8*>(brow + kh*32);
                short8 b1 = *reinterpret_cast<const short8*>(brow + 16*BS_STR + kh*32);
                short8 b2 = *reinterpret_cast<const short8*>(brow + 32*BS_STR + kh*32);
                short8 b3 = *reinterpret_cast<const short8*>(brow + 48*BS_STR + kh*32);
                acc[0][0] = __builtin_amdgcn_mfma_f32_16x16x32_bf16(a0, b0, acc[0][0], 0, 0, 0);
                acc[0][1] = __builtin_amdgcn_mfma_f32_16x16x32_bf16(a0, b1, acc[0][1], 0, 0, 0);
                acc[0][2] = __builtin_amdgcn_mfma_f32_16x16x32_bf16(a0, b2, acc[0][2], 0, 0, 0);
                acc[0][3] = __builtin_amdgcn_mfma_f32_16x16x32_bf16(a0, b3, acc[0][3], 0, 0, 0);
                acc[1][0] = __builtin_amdgcn_mfma_f32_16x16x32_bf16(a1, b0, acc[1][0], 0, 0, 0);
                acc[1][1] = __builtin_amdgcn_mfma_f32_16x16x32_bf16(a1, b1, acc[1][1], 0, 0, 0);
                acc[1][2] = __builtin_amdgcn_mfma_f32_16x16x32_bf16(a1, b2, acc[1][2], 0, 0, 0);
                acc[1][3] = __builtin_amdgcn_mfma_f32_16x16x32_bf16(a1, b3, acc[1][3], 0, 0, 0);
            }
        }

        // --- deterministic b2 reduction ---
        b2p[(srow)      * 4 + (tid & 3)] = b2acc0;
        b2p[(srow + 64) * 4 + (tid & 3)] = b2acc1;
        __syncthreads();
        if (tid < 128)
            b2s[tid] = b2p[tid*4] + b2p[tid*4+1] + b2p[tid*4+2] + b2p[tid*4+3];
        __syncthreads();

        // --- dump s = b2 - 2*cross into sd ---
        // C/D layout (16x16x32 bf16, verified): col = lane&15, row = (lane>>4)*4 + reg
#pragma unroll
        for (int n2 = 0; n2 < 4; ++n2) {
            const int col = 64*wx + 16*n2 + c_lo;
            const float bv = b2s[col];
#pragma unroll
            for (int m2 = 0; m2 < 2; ++m2) {
                const int row = 32*wy + 16*m2 + (r_hi << 2);
#pragma unroll
                for (int rg = 0; rg < 4; ++rg)
                    sd[(row + rg) * SD_STR + col] = bv - 2.0f * acc[m2][n2][rg];
            }
        }
        __syncthreads();

        // --- scan: 4 lanes/row, interleaved cols (conflict-free), top-21 insert ---
        {
            const int r  = tid >> 2;
            const int cb = tid & 3;
#pragma unroll 1
            for (int j = 0; j < 32; ++j) {
                const int c = cb + (j << 2);
                if (c < ncols) {
                    float v = sd[r * SD_STR + c];
                    if (v < list[NLIST - 1]) {
#pragma unroll
                        for (int i = 0; i < NLIST; ++i) {
                            const float lo = fminf(list[i], v);
                            const float hi = fmaxf(list[i], v);
                            list[i] = lo;
                            v = hi;
                        }
                    }
                }
            }
        }
        __syncthreads();   // scan done before next tile overwrites sd
    }

    // --- merge 4 per-lane sub-lists per row -> sorted 21, write to workspace ---
#pragma unroll
    for (int i = 0; i < NLIST; ++i) mg[tid * 22 + i] = list[i];
    __syncthreads();

    if ((tid & 3) == 0) {
        const int row = tid >> 2;
        float* outp = lists + ((size_t)((l * B_) + qt * 64 + row) * NC_ + nc) * LPAD;
        int p0 = 0, p1 = 0, p2 = 0, p3 = 0;
#pragma unroll 1
        for (int i = 0; i < NLIST; ++i) {
            const float h0 = (p0 < NLIST) ? mg[(tid + 0) * 22 + p0] : BIGF;
            const float h1 = (p1 < NLIST) ? mg[(tid + 1) * 22 + p1] : BIGF;
            const float h2 = (p2 < NLIST) ? mg[(tid + 2) * 22 + p2] : BIGF;
            const float h3 = (p3 < NLIST) ? mg[(tid + 3) * 22 + p3] : BIGF;
            const float mv = fminf(fminf(h0, h1), fminf(h2, h3));
            if (h0 == mv)      ++p0;
            else if (h1 == mv) ++p1;
            else if (h2 == mv) ++p2;
            else               ++p3;
            outp[i] = mv;
        }
    }
}

// ---------------- Phase 3: merge 32 sorted chunk-lists per (l,b), compute LID ----
__global__ void lid_kernel(const float* __restrict__ lists,
                           const float* __restrict__ q,
                           float* __restrict__ out)
{
    __shared__ float pops[4][NLIST];
    const int lane = threadIdx.x & 63;
    const int w    = threadIdx.x >> 6;
    const int gw   = blockIdx.x * 4 + w;   // 0..1023 = (l,b)
    const int l    = gw & 3;
    const int b    = gw >> 2;

    const float* qr = q + ((size_t)l * B_ + b) * C_;
    float q2 = 0.0f;
#pragma unroll
    for (int i = 0; i < 8; ++i) {
        const float v = qr[lane + (i << 6)];
        q2 += v * v;
    }
    q2 += __shfl_xor(q2, 1);
    q2 += __shfl_xor(q2, 2);
    q2 += __shfl_xor(q2, 4);
    q2 += __shfl_xor(q2, 8);
    q2 += __shfl_xor(q2, 16);
    q2 += __shfl_xor(q2, 32);

    const float* lb = lists + (size_t)((l * B_ + b) * NC_) * LPAD;
    int ptr = 0;
#pragma unroll 1
    for (int i = 0; i < NLIST; ++i) {
        float h = (lane < NC_ && ptr < NLIST) ? lb[lane * LPAD + ptr] : BIGF;
        float m = h;
        m = fminf(m, __shfl_xor(m, 1));
        m = fminf(m, __shfl_xor(m, 2));
        m = fminf(m, __shfl_xor(m, 4));
        m = fminf(m, __shfl_xor(m, 8));
        m = fminf(m, __shfl_xor(m, 16));
        m = fminf(m, __shfl_xor(m, 32));
        const unsigned long long ball = __ballot(h == m);
        if (lane == __ffsll(ball) - 1) ++ptr;
        if (lane == 0) pops[w][i] = fmaxf(q2 + m, 0.0f);
    }
    __syncthreads();

    const float r2 = pops[w][NLIST - 1];
    float t = 0.0f;
    if (lane >= 1 && lane < NLIST) t = 0.5f * logf(pops[w][lane] / r2);
    t += __shfl_xor(t, 1);
    t += __shfl_xor(t, 2);
    t += __shfl_xor(t, 4);
    t += __shfl_xor(t, 8);
    t += __shfl_xor(t, 16);
    t += __shfl_xor(t, 32);

    if (lane == 0) out[(size_t)b * L_ + l] = -(float)K_ / t;
}

extern "C" void kernel_launch(void* const* d_in, const int* in_sizes, int n_in,
                              void* d_out, int out_size, void* d_ws, size_t ws_size,
                              hipStream_t stream)
{
    (void)in_sizes; (void)n_in; (void)out_size; (void)ws_size;
    const float* feats = (const float*)d_in[0];
    const float* bank  = (const float*)d_in[1];
    float* q     = (float*)d_ws;                       // L*B*C fp32 = 2 MiB
    float* lists = q + (size_t)L_ * B_ * C_;           // L*B*NC*LPAD fp32 = 3 MiB

    qmean_kernel<<<32768, 256, 0, stream>>>(feats, q);
    dist_topk_kernel<<<512, 256, 0, stream>>>(bank, q, lists);
    lid_kernel<<<256, 256, 0, stream>>>(lists, q, (float*)d_out);
}